// Round 10
// baseline (305.657 us; speedup 1.0000x reference)
//
#include <hip/hip_runtime.h>

// ---------------------------------------------------------------------------
// ModulatedConvBlock on MI355X (gfx950) — round 10
// Serial-cost model: time ≈ MFMA + LDS-bytes + per-phase OH (no overlap).
// => minimize LDS bytes/MFMA with a 2x register tile.
// Conv: 1 block/CU (grid 256, 256 thr, 4 waves @ 1 wave/SIMD).
// Wave = 128 cout x 128 sp (2 rows x 64 w): acc 16 x f32x16 = 256 AGPR,
// reads 16 b128 per 32 MFMA (0.5 reads/MFMA vs 0.75 in R9).
// Weights: LDS ring[3], staged tap+2 ahead (8 gld16/thr). xm: LDS dbuf,
// staged by gld16 at tap0 (aged 9 phases). ONE barrier per phase,
// counted vmcnt(8). Both operands XOR-bank-swizzled (key (row>>1)&3).
// ---------------------------------------------------------------------------

typedef short bf16x8 __attribute__((ext_vector_type(8)));
typedef short short8v __attribute__((ext_vector_type(8)));
typedef float f32x16 __attribute__((ext_vector_type(16)));

// workspace layout (bytes)
#define WS_STYLE 0            // [8][512] f32
#define WS_DEMOD 16384        // [8][512] f32
#define WS_WSQ   32768        // [512][512] f32
#define WS_WPACK 1081344      // [tap9][cc16][o512][sp4][8] bf16 (4718592 B)
#define WS_XM    5799936      // [8][66][66][512] bf16 (35684352 B)

__device__ __forceinline__ short f2bf(float f) {
  unsigned u = __float_as_uint(f);
  u += 0x7FFFu + ((u >> 16) & 1u);   // round-to-nearest-even
  return (short)(u >> 16);
}

__device__ __forceinline__ void gld16(const short* g, char* l) {
  __builtin_amdgcn_global_load_lds((const __attribute__((address_space(1))) void*)g,
                                   (__attribute__((address_space(3))) void*)l,
                                   16, 0, 0);
}

// ---------------- style_std[b][i] = (sb[b]*0.0625) @ aw[i] + ab[i] + 1 ------
__global__ void k_style(const float* __restrict__ sb, const float* __restrict__ aw,
                        const float* __restrict__ ab, float* __restrict__ style) {
  __shared__ float s_sb[512];
  int b = blockIdx.x;
  for (int i = threadIdx.x; i < 512; i += 256) s_sb[i] = sb[b * 512 + i] * 0.0625f;
  __syncthreads();
  for (int i = threadIdx.x; i < 512; i += 256) {
    const float4* wrow = (const float4*)(aw + (size_t)i * 512);
    float acc = 0.f;
    #pragma unroll 4
    for (int s4 = 0; s4 < 128; ++s4) {
      float4 w4 = wrow[s4];
      float4 sv = *(const float4*)(s_sb + s4 * 4);
      acc += w4.x * sv.x + w4.y * sv.y + w4.z * sv.z + w4.w * sv.w;
    }
    style[b * 512 + i] = acc + ab[i] + 1.0f;
  }
}

// ---------------- wsq[o][i] = sum_tap conv_w^2 ------------------------------
__global__ void k_wsq(const float* __restrict__ cw, float* __restrict__ wsq) {
  int idx = blockIdx.x * 256 + threadIdx.x;   // o*512+i
  const float* p = cw + (size_t)idx * 9;
  float s = 0.f;
  #pragma unroll
  for (int j = 0; j < 9; ++j) s += p[j] * p[j];
  wsq[idx] = s;
}

// ---------------- demod[b][o] = rsqrt(sum_i wsq[o][i]*style^2 + eps) --------
__global__ void k_demod(const float* __restrict__ wsq, const float* __restrict__ style,
                        float* __restrict__ demod) {
  int wid = threadIdx.x >> 6, lane = threadIdx.x & 63;
  int idx = blockIdx.x * 4 + wid;             // (b,o)
  int b = idx >> 9, o = idx & 511;
  const float* wr = wsq + (size_t)o * 512;
  const float* ss = style + b * 512;
  float sum = 0.f;
  #pragma unroll
  for (int k = 0; k < 8; ++k) {
    int i = k * 64 + lane;
    float s = ss[i];
    sum += wr[i] * s * s;
  }
  #pragma unroll
  for (int off = 32; off; off >>= 1) sum += __shfl_down(sum, off);
  if (lane == 0) demod[b * 512 + o] = rsqrtf(sum + 1e-8f);
}

// ---------------- upsample 2x bilinear (half-pixel) + modulate, NHWC pad ----
__global__ void k_upsample(const float* __restrict__ x, const float* __restrict__ style,
                           short* __restrict__ xm) {
  int b = blockIdx.x / 66, hp = blockIdx.x % 66;
  short* xmp = xm + ((size_t)b * 66 + hp) * 66 * 512;
  if (hp == 0 || hp == 65) {
    short8v z = {0, 0, 0, 0, 0, 0, 0, 0};
    for (int u = threadIdx.x; u < 66 * 512 / 8; u += 256) ((short8v*)xmp)[u] = z;
    return;
  }
  int h = hp - 1;
  int j0 = (h >> 1) - 1 + (h & 1);
  float fj = (h & 1) ? 0.25f : 0.75f;
  int j0c = j0 < 0 ? 0 : j0;
  int j1c = j0 + 1 > 31 ? 31 : j0 + 1;
  __shared__ float xt[2][64][33];
  int ccc = threadIdx.x & 63;
  int wsub = threadIdx.x >> 6;
  for (int c0 = 0; c0 < 512; c0 += 64) {
    __syncthreads();
    #pragma unroll 4
    for (int k = 0; k < 16; ++k) {
      int idx = k * 256 + threadIdx.x;
      int ii = idx & 31, cc = (idx >> 5) & 63, jj = idx >> 11;
      xt[jj][cc][ii] = x[(((size_t)b * 512 + c0 + cc) * 32 + (jj ? j1c : j0c)) * 32 + ii];
    }
    __syncthreads();
    float sstyle = style[b * 512 + c0 + ccc];
    #pragma unroll 4
    for (int wk = 0; wk < 16; ++wk) {
      int w = wk * 4 + wsub;
      int i0 = (w >> 1) - 1 + (w & 1);
      float fi = (w & 1) ? 0.25f : 0.75f;
      int i0c = i0 < 0 ? 0 : i0;
      int i1c = i0 + 1 > 31 ? 31 : i0 + 1;
      float v0 = xt[0][ccc][i0c] * (1.f - fi) + xt[0][ccc][i1c] * fi;
      float v1 = xt[1][ccc][i0c] * (1.f - fi) + xt[1][ccc][i1c] * fi;
      float v = (v0 * (1.f - fj) + v1 * fj) * sstyle;
      xmp[(size_t)(w + 1) * 512 + c0 + ccc] = f2bf(v);
    }
    if (wsub == 0) {
      xmp[c0 + ccc] = 0;
      xmp[(size_t)65 * 512 + c0 + ccc] = 0;
    }
  }
}

// ---------------- weight pack WITH bank pre-swizzle -------------------------
// wpk[tap][cc][o][sp][j] = w[o][ cc*32 + (sp ^ ((o>>1)&3))*8 + j ][tap]
__global__ void k_packw(const float* __restrict__ cw, short* __restrict__ wpk) {
  int unit = blockIdx.x * 256 + threadIdx.x;  // < 294912
  int s = unit >> 11;                          // tap*16+cc
  int rem = unit & 2047;
  int o = rem >> 2, sp = rem & 3;
  int tap = s >> 4, cc = s & 15;
  int i0 = cc * 32 + ((sp ^ ((o >> 1) & 3)) << 3);
  const float* src = cw + ((size_t)o * 512 + i0) * 9 + tap;
  short8v v;
  #pragma unroll
  for (int j = 0; j < 8; ++j) v[j] = f2bf(src[j * 9]);
  *(short8v*)(wpk + (size_t)unit * 8) = v;
}

// ---------------- main conv: 1 block/CU, 4 waves, 2x register tile ----------
// grid 256 = 32hpair x 8b ; block 256 thr
// wave wo in {0..3}: 128 cout x (2 rows x 64 w) = 128x128 per wave
__global__ __launch_bounds__(256, 1) void k_conv(
    const short* __restrict__ xm, const short* __restrict__ wpk,
    const float* __restrict__ demod, const float* __restrict__ convb,
    const float* __restrict__ nscal, const float* __restrict__ noise,
    const float* __restrict__ t, const float* __restrict__ prelu_a,
    float* __restrict__ y) {
  __shared__ char WTs[3][32768];   // ring: [512 o][4 sp]x16B per tap slot
  __shared__ char XMs[2][16896];   // [4 r][66 wp][4 slot]x16B per buffer

  int tid = threadIdx.x;
  int bid = blockIdx.x;
  int hpair = bid & 31, b = bid >> 5;
  int wo = tid >> 6, lane = tid & 63;
  int l31 = lane & 31, lg = lane >> 5;

  const short* xb = xm + ((size_t)b * 66 + hpair * 2) * 66 * 512;
  int wb0 = ((wo * 128 + l31) << 6) + ((lg ^ ((l31 >> 1) & 3)) << 4);

  // per-thread xm staging units: u = k*256+tid (k=0..3) + tail u=1024+tid (tid<32)
  int xoff[5], xdst[5];
  #pragma unroll
  for (int k = 0; k < 4; ++k) {
    int u = k * 256 + tid;
    int r = u / 264, rem = u - r * 264;
    int wp = rem >> 2, sp = rem & 3;
    xoff[k] = (r * 66 + wp) * 512 + ((sp ^ ((wp >> 1) & 3)) << 3);
    xdst[k] = u * 16;
  }
  {
    int u = 1024 + (tid & 31);     // r = 3 tail (only tid<32 issues)
    int rem = u - 792;
    int wp = rem >> 2, sp = rem & 3;
    xoff[4] = (3 * 66 + wp) * 512 + ((sp ^ ((wp >> 1) & 3)) << 3);
    xdst[4] = u * 16;
  }

  // ---- prologue: XM(cc0) + WT taps 0,1 of cc0 ----
  #pragma unroll
  for (int k = 0; k < 4; ++k) gld16(xb + xoff[k], XMs[0] + xdst[k]);
  if (tid < 32) gld16(xb + xoff[4], XMs[0] + xdst[4]);
  #pragma unroll
  for (int tt = 0; tt < 2; ++tt) {
    const short* ws = wpk + (size_t)(tt * 16) * 16384;
    #pragma unroll
    for (int j = 0; j < 8; ++j)
      gld16(ws + (j * 256 + tid) * 8, WTs[tt] + (j * 256 + tid) * 16);
  }

  f32x16 zf = {0,0,0,0,0,0,0,0,0,0,0,0,0,0,0,0};
  f32x16 acc[4][2][2];             // [cf][rr][sf] = 16 x f32x16 = 256 AGPR
  #pragma unroll
  for (int i = 0; i < 4; ++i)
    #pragma unroll
    for (int j = 0; j < 2; ++j) { acc[i][j][0] = zf; acc[i][j][1] = zf; }

  asm volatile("s_waitcnt vmcnt(0)" ::: "memory");
  __builtin_amdgcn_s_barrier();
  __builtin_amdgcn_sched_barrier(0);

  #pragma unroll 1
  for (int cc = 0; cc < 16; ++cc) {
    const char* XMc = XMs[cc & 1];
    char* XMn = (char*)XMs[(cc & 1) ^ 1];
    #pragma unroll
    for (int tp = 0; tp < 9; ++tp) {
      const int kh = tp / 3, kw = tp % 3;

      // A. stage WT for phase+2 (8 gld16, uniform) — skip at very end
      if (!(cc == 15 && tp >= 7)) {
        const int ntap = (tp + 2) % 9;
        int ncc = cc + (tp >= 7 ? 1 : 0);
        const short* ws = wpk + (size_t)(ntap * 16 + ncc) * 16384;
        char* wd = (char*)WTs[(tp + 2) % 3];
        #pragma unroll
        for (int j = 0; j < 8; ++j)
          gld16(ws + (j * 256 + tid) * 8, wd + (j * 256 + tid) * 16);
      }
      // B. stage xm for cc+1 (aged 9 phases before first read)
      if (tp == 0 && cc < 15) {
        const short* xs = xb + (cc + 1) * 32;
        #pragma unroll
        for (int k = 0; k < 4; ++k) gld16(xs + xoff[k], XMn + xdst[k]);
        if (tid < 32) gld16(xs + xoff[4], XMn + xdst[4]);
      }

      // C. ds_read operands: 8 weight + 8 xm b128 (both swizzled)
      const char* Wp = (const char*)WTs[tp % 3];
      bf16x8 wf0[4], wf1[4];
      #pragma unroll
      for (int cf = 0; cf < 4; ++cf) {
        wf0[cf] = *(const bf16x8*)(Wp + (wb0 + cf * 2048));
        wf1[cf] = *(const bf16x8*)(Wp + ((wb0 + cf * 2048) ^ 32));
      }
      int a = l31 + kw;
      int swz = (lg ^ ((a >> 1) & 3)) << 4;
      bf16x8 xf0[2][2], xf1[2][2];   // [rr][sf], K-half 0/1
      #pragma unroll
      for (int rr = 0; rr < 2; ++rr) {
        int xo = ((rr + kh) * 66 + a) * 64 + swz;
        xf0[rr][0] = *(const bf16x8*)(XMc + xo);
        xf0[rr][1] = *(const bf16x8*)(XMc + xo + 2048);
        xf1[rr][0] = *(const bf16x8*)(XMc + (xo ^ 32));
        xf1[rr][1] = *(const bf16x8*)(XMc + ((xo ^ 32) + 2048));
      }

      // D. 32 MFMA
      __builtin_amdgcn_s_setprio(1);
      #pragma unroll
      for (int cf = 0; cf < 4; ++cf)
        #pragma unroll
        for (int rr = 0; rr < 2; ++rr)
          #pragma unroll
          for (int sf = 0; sf < 2; ++sf)
            acc[cf][rr][sf] = __builtin_amdgcn_mfma_f32_32x32x16_bf16(
                wf0[cf], xf0[rr][sf], acc[cf][rr][sf], 0, 0, 0);
      #pragma unroll
      for (int cf = 0; cf < 4; ++cf)
        #pragma unroll
        for (int rr = 0; rr < 2; ++rr)
          #pragma unroll
          for (int sf = 0; sf < 2; ++sf)
            acc[cf][rr][sf] = __builtin_amdgcn_mfma_f32_32x32x16_bf16(
                wf1[cf], xf1[rr][sf], acc[cf][rr][sf], 0, 0, 0);
      __builtin_amdgcn_s_setprio(0);

      // E. counted end-of-phase wait (never 0 mid-loop), single barrier.
      //    Safe with one barrier: this wave's ds_reads retired before its
      //    MFMAs (lgkm waits); peers' writes to ring slot tp%3 are issued
      //    only after they pass this barrier.
      if (cc == 15 && tp >= 7)
        asm volatile("s_waitcnt vmcnt(0)" ::: "memory");
      else
        asm volatile("s_waitcnt vmcnt(8)" ::: "memory");
      __builtin_amdgcn_s_barrier();
      __builtin_amdgcn_sched_barrier(0);
    }
  }

  // ---- epilogue: demod + bias + noise + prelu + (y+t)/sqrt2 ----
  float pa = prelu_a[0];
  const float inv_r2 = 1.0f / 1.41421f;
  #pragma unroll
  for (int cf = 0; cf < 4; ++cf) {
    #pragma unroll
    for (int reg = 0; reg < 16; ++reg) {
      int orow = (reg & 3) + 8 * (reg >> 2) + 4 * lg;
      int o = wo * 128 + cf * 32 + orow;
      float dm = demod[b * 512 + o];
      float cb = convb[o];
      float ns = nscal[o];
      #pragma unroll
      for (int rr = 0; rr < 2; ++rr) {
        int h = hpair * 2 + rr;
        #pragma unroll
        for (int sf = 0; sf < 2; ++sf) {
          int w = sf * 32 + l31;
          float v = acc[cf][rr][sf][reg];
          v = v * dm + cb + ns * noise[((size_t)b * 64 + h) * 64 + w];
          v = (v >= 0.f) ? v : pa * v;
          size_t oi = (((size_t)b * 512 + o) * 64 + h) * 64 + w;
          v = (v + t[oi]) * inv_r2;
          y[oi] = v;
        }
      }
    }
  }
}

// ---------------- toRGB: 1x1 conv over 512 ch + clamp -----------------------
__global__ void k_rgb(const float* __restrict__ y, const float* __restrict__ ow,
                      const float* __restrict__ ob, float* __restrict__ out) {
  int b = blockIdx.x >> 6, h = blockIdx.x & 63;
  int w = threadIdx.x & 63, g = threadIdx.x >> 6;
  const float* yb = y + (((size_t)b * 512) * 64 + h) * 64 + w;
  float s0 = 0.f, s1 = 0.f, s2 = 0.f;
  for (int o = g * 128; o < g * 128 + 128; ++o) {
    float v = yb[(size_t)o * 4096];
    s0 += v * ow[o];
    s1 += v * ow[512 + o];
    s2 += v * ow[1024 + o];
  }
  __shared__ float red[3][4][64];
  red[0][g][w] = s0; red[1][g][w] = s1; red[2][g][w] = s2;
  __syncthreads();
  if (threadIdx.x < 192) {
    int c = threadIdx.x >> 6, ww = threadIdx.x & 63;
    float s = red[c][0][ww] + red[c][1][ww] + red[c][2][ww] + red[c][3][ww];
    s = s * 0.0625f + ob[c];
    s = fminf(fmaxf(s, 0.f), 1.f);
    out[(((size_t)b * 3 + c) * 64 + h) * 64 + ww] = s;
  }
}

extern "C" void kernel_launch(void* const* d_in, const int* in_sizes, int n_in,
                              void* d_out, int out_size, void* d_ws, size_t ws_size,
                              hipStream_t stream) {
  const float* x     = (const float*)d_in[0];
  const float* sb    = (const float*)d_in[1];
  const float* noise = (const float*)d_in[2];
  const float* t     = (const float*)d_in[3];
  const float* aw    = (const float*)d_in[4];
  const float* ab    = (const float*)d_in[5];
  const float* cw    = (const float*)d_in[6];
  const float* cb    = (const float*)d_in[7];
  const float* pa    = (const float*)d_in[8];
  const float* ns    = (const float*)d_in[9];
  const float* ow    = (const float*)d_in[10];
  const float* ob    = (const float*)d_in[11];
  char* ws = (char*)d_ws;
  float* style = (float*)(ws + WS_STYLE);
  float* demod = (float*)(ws + WS_DEMOD);
  float* wsq   = (float*)(ws + WS_WSQ);
  short* wpk   = (short*)(ws + WS_WPACK);
  short* xmw   = (short*)(ws + WS_XM);
  float* y   = (float*)d_out;
  float* out = y + 16777216;

  k_style<<<8, 256, 0, stream>>>(sb, aw, ab, style);
  k_wsq<<<1024, 256, 0, stream>>>(cw, wsq);
  k_demod<<<1024, 256, 0, stream>>>(wsq, style, demod);
  k_upsample<<<528, 256, 0, stream>>>(x, style, xmw);
  k_packw<<<1152, 256, 0, stream>>>(cw, wpk);
  k_conv<<<256, 256, 0, stream>>>(xmw, wpk, demod, cb, ns, noise, t, pa, y);
  k_rgb<<<512, 256, 0, stream>>>(y, ow, ob, out);
}

// Round 11
// 227.084 us; speedup vs baseline: 1.3460x; 1.3460x over previous
//
#include <hip/hip_runtime.h>

// ---------------------------------------------------------------------------
// ModulatedConvBlock on MI355X (gfx950) — round 11
// Conv: bf16 MFMA implicit GEMM, 3-tap MEGA-PHASES (48 phases total),
// 1 block/CU (grid 256, 512 thr, 8 waves), wave = 128co x 64sp.
// WT ring[6] 16KB tap-slabs (parity-alternating triples, staged 1 mega-phase
// ahead); xm 6-row dbuf staged at krow0. ONE barrier + vmcnt(0) per phase
// (loads aged a full ~3500-cyc mega-phase -> drain is cheap). No inter-tap
// barriers: compiler interleaves 36 ds_reads with 48 MFMAs per phase.
// ---------------------------------------------------------------------------

typedef short bf16x8 __attribute__((ext_vector_type(8)));
typedef short short8v __attribute__((ext_vector_type(8)));
typedef float f32x16 __attribute__((ext_vector_type(16)));

// workspace layout (bytes)
#define WS_STYLE 0            // [8][512] f32
#define WS_DEMOD 16384        // [8][512] f32
#define WS_WSQ   32768        // [512][512] f32
#define WS_WPACK 1081344      // [tap9][cc16][o512][sp4][8] bf16 (4718592 B)
#define WS_XM    5799936      // [8][66][66][512] bf16 (35684352 B)

__device__ __forceinline__ short f2bf(float f) {
  unsigned u = __float_as_uint(f);
  u += 0x7FFFu + ((u >> 16) & 1u);   // round-to-nearest-even
  return (short)(u >> 16);
}

__device__ __forceinline__ void gld16(const short* g, char* l) {
  __builtin_amdgcn_global_load_lds((const __attribute__((address_space(1))) void*)g,
                                   (__attribute__((address_space(3))) void*)l,
                                   16, 0, 0);
}

// ---------------- style_std[b][i] = (sb[b]*0.0625) @ aw[i] + ab[i] + 1 ------
__global__ void k_style(const float* __restrict__ sb, const float* __restrict__ aw,
                        const float* __restrict__ ab, float* __restrict__ style) {
  __shared__ float s_sb[512];
  int b = blockIdx.x;
  for (int i = threadIdx.x; i < 512; i += 256) s_sb[i] = sb[b * 512 + i] * 0.0625f;
  __syncthreads();
  for (int i = threadIdx.x; i < 512; i += 256) {
    const float4* wrow = (const float4*)(aw + (size_t)i * 512);
    float acc = 0.f;
    #pragma unroll 4
    for (int s4 = 0; s4 < 128; ++s4) {
      float4 w4 = wrow[s4];
      float4 sv = *(const float4*)(s_sb + s4 * 4);
      acc += w4.x * sv.x + w4.y * sv.y + w4.z * sv.z + w4.w * sv.w;
    }
    style[b * 512 + i] = acc + ab[i] + 1.0f;
  }
}

// ---------------- wsq[o][i] = sum_tap conv_w^2 ------------------------------
__global__ void k_wsq(const float* __restrict__ cw, float* __restrict__ wsq) {
  int idx = blockIdx.x * 256 + threadIdx.x;   // o*512+i
  const float* p = cw + (size_t)idx * 9;
  float s = 0.f;
  #pragma unroll
  for (int j = 0; j < 9; ++j) s += p[j] * p[j];
  wsq[idx] = s;
}

// ---------------- demod[b][o] = rsqrt(sum_i wsq[o][i]*style^2 + eps) --------
__global__ void k_demod(const float* __restrict__ wsq, const float* __restrict__ style,
                        float* __restrict__ demod) {
  int wid = threadIdx.x >> 6, lane = threadIdx.x & 63;
  int idx = blockIdx.x * 4 + wid;             // (b,o)
  int b = idx >> 9, o = idx & 511;
  const float* wr = wsq + (size_t)o * 512;
  const float* ss = style + b * 512;
  float sum = 0.f;
  #pragma unroll
  for (int k = 0; k < 8; ++k) {
    int i = k * 64 + lane;
    float s = ss[i];
    sum += wr[i] * s * s;
  }
  #pragma unroll
  for (int off = 32; off; off >>= 1) sum += __shfl_down(sum, off);
  if (lane == 0) demod[b * 512 + o] = rsqrtf(sum + 1e-8f);
}

// ---------------- upsample 2x bilinear (half-pixel) + modulate, NHWC pad ----
__global__ void k_upsample(const float* __restrict__ x, const float* __restrict__ style,
                           short* __restrict__ xm) {
  int b = blockIdx.x / 66, hp = blockIdx.x % 66;
  short* xmp = xm + ((size_t)b * 66 + hp) * 66 * 512;
  if (hp == 0 || hp == 65) {
    short8v z = {0, 0, 0, 0, 0, 0, 0, 0};
    for (int u = threadIdx.x; u < 66 * 512 / 8; u += 256) ((short8v*)xmp)[u] = z;
    return;
  }
  int h = hp - 1;
  int j0 = (h >> 1) - 1 + (h & 1);
  float fj = (h & 1) ? 0.25f : 0.75f;
  int j0c = j0 < 0 ? 0 : j0;
  int j1c = j0 + 1 > 31 ? 31 : j0 + 1;
  __shared__ float xt[2][64][33];
  int ccc = threadIdx.x & 63;
  int wsub = threadIdx.x >> 6;
  for (int c0 = 0; c0 < 512; c0 += 64) {
    __syncthreads();
    #pragma unroll 4
    for (int k = 0; k < 16; ++k) {
      int idx = k * 256 + threadIdx.x;
      int ii = idx & 31, cc = (idx >> 5) & 63, jj = idx >> 11;
      xt[jj][cc][ii] = x[(((size_t)b * 512 + c0 + cc) * 32 + (jj ? j1c : j0c)) * 32 + ii];
    }
    __syncthreads();
    float sstyle = style[b * 512 + c0 + ccc];
    #pragma unroll 4
    for (int wk = 0; wk < 16; ++wk) {
      int w = wk * 4 + wsub;
      int i0 = (w >> 1) - 1 + (w & 1);
      float fi = (w & 1) ? 0.25f : 0.75f;
      int i0c = i0 < 0 ? 0 : i0;
      int i1c = i0 + 1 > 31 ? 31 : i0 + 1;
      float v0 = xt[0][ccc][i0c] * (1.f - fi) + xt[0][ccc][i1c] * fi;
      float v1 = xt[1][ccc][i0c] * (1.f - fi) + xt[1][ccc][i1c] * fi;
      float v = (v0 * (1.f - fj) + v1 * fj) * sstyle;
      xmp[(size_t)(w + 1) * 512 + c0 + ccc] = f2bf(v);
    }
    if (wsub == 0) {
      xmp[c0 + ccc] = 0;
      xmp[(size_t)65 * 512 + c0 + ccc] = 0;
    }
  }
}

// ---------------- weight pack WITH bank pre-swizzle -------------------------
// wpk[tap][cc][o][sp][j] = w[o][ cc*32 + (sp ^ ((o>>1)&3))*8 + j ][tap]
__global__ void k_packw(const float* __restrict__ cw, short* __restrict__ wpk) {
  int unit = blockIdx.x * 256 + threadIdx.x;  // < 294912
  int s = unit >> 11;                          // tap*16+cc
  int rem = unit & 2047;
  int o = rem >> 2, sp = rem & 3;
  int tap = s >> 4, cc = s & 15;
  int i0 = cc * 32 + ((sp ^ ((o >> 1) & 3)) << 3);
  const float* src = cw + ((size_t)o * 512 + i0) * 9 + tap;
  short8v v;
  #pragma unroll
  for (int j = 0; j < 8; ++j) v[j] = f2bf(src[j * 9]);
  *(short8v*)(wpk + (size_t)unit * 8) = v;
}

// ---------------- main conv: 3-tap mega-phases, ring[6] weight slabs --------
// grid 256 = 2cohalf x 16hq x 8b ; block 512 thr, 8 waves
// wave (wo in {0,1}, wsrow in {0..3}): 128 cout x row(hq*4+wsrow) x 64 w
__global__ __launch_bounds__(512, 2) void k_conv(
    const short* __restrict__ xm, const short* __restrict__ wpk,
    const float* __restrict__ demod, const float* __restrict__ convb,
    const float* __restrict__ nscal, const float* __restrict__ noise,
    const float* __restrict__ t, const float* __restrict__ prelu_a,
    float* __restrict__ y) {
  __shared__ char WTs[2][49152];   // parity: 3 slabs x [256 o][4 sp]x16B
  __shared__ char XMs[2][25344];   // [6 r][66 wp][4 slot]x16B per buffer

  int tid = threadIdx.x;
  int bid = blockIdx.x;
  int cohalf = bid & 1, hq = (bid >> 1) & 15, b = bid >> 5;
  int wid = tid >> 6, lane = tid & 63;
  int wo = wid & 1, wsrow = wid >> 1;
  int l31 = lane & 31, lg = lane >> 5;

  const short* xb = xm + ((size_t)b * 66 + hq * 4) * 66 * 512;
  const short* wpkh = wpk + (size_t)cohalf * 256 * 32;  // this block's 256 couts
  int wb0 = ((wo * 128 + l31) << 6) + ((lg ^ ((l31 >> 1) & 3)) << 4);

  // ---- prologue: XM(cc0, 1584 units) + WT slabs for phase 0 (taps 0..2) ----
  #pragma unroll
  for (int k = 0; k < 3; ++k) {
    int u = k * 512 + tid;
    int r = u / 264, rem = u - r * 264;
    int wp = rem >> 2, sp = rem & 3;
    gld16(xb + (size_t)(r * 66 + wp) * 512 + ((sp ^ ((wp >> 1) & 3)) << 3), XMs[0] + u * 16);
  }
  if (tid < 48) {
    int u = 1536 + tid;
    int rem = u - 1320;             // r = 5
    int wp = rem >> 2, sp = rem & 3;
    gld16(xb + (size_t)(5 * 66 + wp) * 512 + ((sp ^ ((wp >> 1) & 3)) << 3), XMs[0] + u * 16);
  }
  #pragma unroll
  for (int j = 0; j < 3; ++j) {
    const short* ws = wpkh + (size_t)(j * 16) * 16384;   // tap j, cc0
    gld16(ws + tid * 8, WTs[0] + j * 16384 + tid * 16);
    gld16(ws + (512 + tid) * 8, WTs[0] + j * 16384 + (512 + tid) * 16);
  }

  f32x16 zf = {0,0,0,0,0,0,0,0,0,0,0,0,0,0,0,0};
  f32x16 acc[4][2];
  #pragma unroll
  for (int i = 0; i < 4; ++i) { acc[i][0] = zf; acc[i][1] = zf; }

  asm volatile("s_waitcnt vmcnt(0)" ::: "memory");
  __builtin_amdgcn_s_barrier();
  __builtin_amdgcn_sched_barrier(0);

  #pragma unroll 1
  for (int cc = 0; cc < 16; ++cc) {
    const char* XMc = XMs[cc & 1];
    char* XMn = (char*)XMs[(cc & 1) ^ 1];
    #pragma unroll
    for (int krow = 0; krow < 3; ++krow) {
      int g = cc * 3 + krow;
      const char* WTc = WTs[g & 1];
      char* WTn = (char*)WTs[(g & 1) ^ 1];

      // A. stage next mega-phase's 3 weight slabs (6 gld16, uniform)
      if (g < 47) {
        int nkrow = (krow < 2) ? krow + 1 : 0;
        int ncc = (krow < 2) ? cc : cc + 1;
        #pragma unroll
        for (int j = 0; j < 3; ++j) {
          const short* ws = wpkh + (size_t)((nkrow * 3 + j) * 16 + ncc) * 16384;
          gld16(ws + tid * 8, WTn + j * 16384 + tid * 16);
          gld16(ws + (512 + tid) * 8, WTn + j * 16384 + (512 + tid) * 16);
        }
      }
      // B. stage xm for cc+1 at krow 0 (aged 3 mega-phases before first read)
      if (krow == 0 && cc < 15) {
        const short* xs = xb + (cc + 1) * 32;
        #pragma unroll
        for (int k = 0; k < 3; ++k) {
          int u = k * 512 + tid;
          int r = u / 264, rem = u - r * 264;
          int wp = rem >> 2, sp = rem & 3;
          gld16(xs + (size_t)(r * 66 + wp) * 512 + ((sp ^ ((wp >> 1) & 3)) << 3), XMn + u * 16);
        }
        if (tid < 48) {
          int u = 1536 + tid;
          int rem = u - 1320;       // r = 5
          int wp = rem >> 2, sp = rem & 3;
          gld16(xs + (size_t)(5 * 66 + wp) * 512 + ((sp ^ ((wp >> 1) & 3)) << 3), XMn + u * 16);
        }
      }

      // C. compute 3 taps (no barriers between — compiler interleaves)
      #pragma unroll
      for (int j = 0; j < 3; ++j) {
        const char* Wp = WTc + j * 16384;
        bf16x8 wf0[4], wf1[4];
        #pragma unroll
        for (int cf = 0; cf < 4; ++cf) {
          wf0[cf] = *(const bf16x8*)(Wp + (wb0 + cf * 2048));
          wf1[cf] = *(const bf16x8*)(Wp + ((wb0 + cf * 2048) ^ 32));
        }
        int a = l31 + j;            // kw = j
        int xo = ((wsrow + krow) * 66 + a) * 64 + ((lg ^ ((a >> 1) & 3)) << 4);
        bf16x8 xf00 = *(const bf16x8*)(XMc + xo);
        bf16x8 xf01 = *(const bf16x8*)(XMc + xo + 2048);
        bf16x8 xf10 = *(const bf16x8*)(XMc + (xo ^ 32));
        bf16x8 xf11 = *(const bf16x8*)(XMc + ((xo ^ 32) + 2048));

        #pragma unroll
        for (int cf = 0; cf < 4; ++cf) {
          acc[cf][0] = __builtin_amdgcn_mfma_f32_32x32x16_bf16(wf0[cf], xf00, acc[cf][0], 0, 0, 0);
          acc[cf][1] = __builtin_amdgcn_mfma_f32_32x32x16_bf16(wf0[cf], xf01, acc[cf][1], 0, 0, 0);
        }
        #pragma unroll
        for (int cf = 0; cf < 4; ++cf) {
          acc[cf][0] = __builtin_amdgcn_mfma_f32_32x32x16_bf16(wf1[cf], xf10, acc[cf][0], 0, 0, 0);
          acc[cf][1] = __builtin_amdgcn_mfma_f32_32x32x16_bf16(wf1[cf], xf11, acc[cf][1], 0, 0, 0);
        }
      }

      // D. end of mega-phase: vmcnt(0) is cheap (loads aged a full phase)
      asm volatile("s_waitcnt vmcnt(0)" ::: "memory");
      __builtin_amdgcn_s_barrier();
      __builtin_amdgcn_sched_barrier(0);
    }
  }

  // ---- epilogue: demod + bias + noise + prelu + (y+t)/sqrt2 ----
  float pa = prelu_a[0];
  const float inv_r2 = 1.0f / 1.41421f;
  int h = hq * 4 + wsrow;
  float nz0 = noise[((size_t)b * 64 + h) * 64 + l31];
  float nz1 = noise[((size_t)b * 64 + h) * 64 + 32 + l31];
  #pragma unroll
  for (int cf = 0; cf < 4; ++cf) {
    #pragma unroll
    for (int reg = 0; reg < 16; ++reg) {
      int orow = (reg & 3) + 8 * (reg >> 2) + 4 * lg;
      int o = cohalf * 256 + wo * 128 + cf * 32 + orow;
      float dm = demod[b * 512 + o];
      float cb = convb[o];
      float ns = nscal[o];
      #pragma unroll
      for (int sf = 0; sf < 2; ++sf) {
        int w = sf * 32 + l31;
        float v = acc[cf][sf][reg];
        v = v * dm + cb + ns * (sf ? nz1 : nz0);
        v = (v >= 0.f) ? v : pa * v;
        size_t oi = (((size_t)b * 512 + o) * 64 + h) * 64 + w;
        v = (v + t[oi]) * inv_r2;
        y[oi] = v;
      }
    }
  }
}

// ---------------- toRGB: 1x1 conv over 512 ch + clamp -----------------------
__global__ void k_rgb(const float* __restrict__ y, const float* __restrict__ ow,
                      const float* __restrict__ ob, float* __restrict__ out) {
  int b = blockIdx.x >> 6, h = blockIdx.x & 63;
  int w = threadIdx.x & 63, g = threadIdx.x >> 6;
  const float* yb = y + (((size_t)b * 512) * 64 + h) * 64 + w;
  float s0 = 0.f, s1 = 0.f, s2 = 0.f;
  for (int o = g * 128; o < g * 128 + 128; ++o) {
    float v = yb[(size_t)o * 4096];
    s0 += v * ow[o];
    s1 += v * ow[512 + o];
    s2 += v * ow[1024 + o];
  }
  __shared__ float red[3][4][64];
  red[0][g][w] = s0; red[1][g][w] = s1; red[2][g][w] = s2;
  __syncthreads();
  if (threadIdx.x < 192) {
    int c = threadIdx.x >> 6, ww = threadIdx.x & 63;
    float s = red[c][0][ww] + red[c][1][ww] + red[c][2][ww] + red[c][3][ww];
    s = s * 0.0625f + ob[c];
    s = fminf(fmaxf(s, 0.f), 1.f);
    out[(((size_t)b * 3 + c) * 64 + h) * 64 + ww] = s;
  }
}

extern "C" void kernel_launch(void* const* d_in, const int* in_sizes, int n_in,
                              void* d_out, int out_size, void* d_ws, size_t ws_size,
                              hipStream_t stream) {
  const float* x     = (const float*)d_in[0];
  const float* sb    = (const float*)d_in[1];
  const float* noise = (const float*)d_in[2];
  const float* t     = (const float*)d_in[3];
  const float* aw    = (const float*)d_in[4];
  const float* ab    = (const float*)d_in[5];
  const float* cw    = (const float*)d_in[6];
  const float* cb    = (const float*)d_in[7];
  const float* pa    = (const float*)d_in[8];
  const float* ns    = (const float*)d_in[9];
  const float* ow    = (const float*)d_in[10];
  const float* ob    = (const float*)d_in[11];
  char* ws = (char*)d_ws;
  float* style = (float*)(ws + WS_STYLE);
  float* demod = (float*)(ws + WS_DEMOD);
  float* wsq   = (float*)(ws + WS_WSQ);
  short* wpk   = (short*)(ws + WS_WPACK);
  short* xmw   = (short*)(ws + WS_XM);
  float* y   = (float*)d_out;
  float* out = y + 16777216;

  k_style<<<8, 256, 0, stream>>>(sb, aw, ab, style);
  k_wsq<<<1024, 256, 0, stream>>>(cw, wsq);
  k_demod<<<1024, 256, 0, stream>>>(wsq, style, demod);
  k_upsample<<<528, 256, 0, stream>>>(x, style, xmw);
  k_packw<<<1152, 256, 0, stream>>>(cw, wpk);
  k_conv<<<256, 512, 0, stream>>>(xmw, wpk, demod, cb, ns, noise, t, pa, y);
  k_rgb<<<512, 256, 0, stream>>>(y, ow, ob, out);
}